// Round 11
// baseline (179.656 us; speedup 1.0000x reference)
//
#include <hip/hip_runtime.h>
#include <hip/hip_bf16.h>
#include <stdint.h>

#define N_ROWS 16384
#define K_DIM  1024
#define N_OUT  4096

typedef __attribute__((ext_vector_type(8))) short short8;
typedef __attribute__((ext_vector_type(8))) __bf16 bf16x8;
typedef __attribute__((ext_vector_type(4))) float f32x4;
typedef __attribute__((ext_vector_type(4))) __bf16 bf16x4;

// ============ PRE-ARRANGED GLOBAL LAYOUT (frag-linear tiles) =================
// A (xb) and B (wb) are stored as 256-row tiles, 16 K-tiles (BK=64), 2 K-halves.
// Unit (T, kt, kh) = 16 KB at byte ((T*32 + kt*2 + kh) * 16384).
// Within a unit: frag f = row>>4 (16 frags x 1KB), lane l = (row&15)|((k''>>3)<<4)
// (k'' = k within the 32-wide half), element e = k&7:  byte = f*1024 + l*16 + e*2.
// This is EXACTLY the MFMA fragment order, so GEMM staging is global_load_lds
// from CONTIGUOUS 8KB runs into linear LDS, and ds_read_b128 is lane-consecutive
// (0 bank conflicts, verified in R6). Reorder cost is paid in the BW-bound
// gather/prep kernels using 16-row groups (writes become 256B coalesced runs).

__device__ __forceinline__ void cvt8_store(const float4 a, const float4 b, __bf16* dst) {
    bf16x8 o;
    o[0] = (__bf16)a.x; o[1] = (__bf16)a.y; o[2] = (__bf16)a.z; o[3] = (__bf16)a.w;
    o[4] = (__bf16)b.x; o[5] = (__bf16)b.y; o[6] = (__bf16)b.z; o[7] = (__bf16)b.w;
    *reinterpret_cast<bf16x8*>(dst) = o;
}

__device__ __forceinline__ size_t frag_off(int tile, int oct, int r /*row in tile*/) {
    const int kt = oct >> 3, kh = (oct >> 2) & 1;
    const int f = r >> 4, l = (r & 15) | ((oct & 3) << 4);
    return (size_t)(tile * 32 + kt * 2 + kh) * 16384 + f * 1024 + l * 16;
}

// ---------------- prep: block 0 = mask scan; blocks 1..256 = W reorder --------
__global__ __launch_bounds__(1024) void prep_kernel(
    const int*   __restrict__ amask,
    const float* __restrict__ W,
    int* __restrict__ idx, int* __restrict__ zidx, int* __restrict__ count,
    __bf16* __restrict__ wb)
{
    const int t = threadIdx.x;
    if (blockIdx.x != 0) {
        // W reorder: group of 16 W-rows (out-cols). rr = t&15, oct = (t>>4)+64*it.
        const int c0 = (blockIdx.x - 1) * 16;
        const int rr = t & 15;
        const int op = t >> 4;                   // 0..63
        const int c  = c0 + rr;
        const float4* src = reinterpret_cast<const float4*>(W + (size_t)c * K_DIM);
#pragma unroll
        for (int it = 0; it < 2; ++it) {
            const int oct = op + 64 * it;        // 0..127
            float4 a = src[oct * 2], b = src[oct * 2 + 1];
            cvt8_store(a, b, (__bf16*)((char*)wb + frag_off(c >> 8, oct, c & 255)));
        }
        return;
    }
    // ---- mask compaction scan ----
    __shared__ int sc[1024];
    const int base = t * 16;
    int mk[16];
#pragma unroll
    for (int g = 0; g < 4; ++g) {
        int4 m4 = reinterpret_cast<const int4*>(amask + base)[g];
        mk[g*4+0] = m4.x; mk[g*4+1] = m4.y; mk[g*4+2] = m4.z; mk[g*4+3] = m4.w;
    }
    int c = 0;
#pragma unroll
    for (int i = 0; i < 16; ++i) c += (mk[i] != 0) ? 1 : 0;
    int v = c;
    sc[t] = v;
    __syncthreads();
    for (int off = 1; off < 1024; off <<= 1) {
        int u = (t >= off) ? sc[t - off] : 0;
        __syncthreads();
        v += u; sc[t] = v;
        __syncthreads();
    }
    int b  = v - c;
    int zb = base - b;
#pragma unroll
    for (int i = 0; i < 16; ++i) {
        int r = base + i;
        if (mk[i] != 0) idx[b++] = r; else zidx[zb++] = r;
    }
    if (t == 1023) count[0] = v;
}

// ---- gather+zfill: blocks 0..1023 gather x rows into frag-layout xb (16-row
//      groups; rows >= cnt zero-padded to the tile edge); blocks 1024..2047
//      zero FULL masked rows of out. --------------------------------------------
__global__ __launch_bounds__(256) void gather_zfill_kernel(
    const float* __restrict__ x, const int* __restrict__ idx,
    const int* __restrict__ zidx, const int* __restrict__ count,
    __bf16* __restrict__ xb, float* __restrict__ out) {
    const int t = threadIdx.x;
    const int cnt = count[0];
    if (blockIdx.x < 1024) {
        const int cntUp = (cnt + 255) & ~255;    // pad to tile edge
        const int ngrp  = cntUp >> 4;            // 16-row groups
        const int rr = t & 15;
        const int op = t >> 4;                   // 0..15
        for (int g = blockIdx.x; g < ngrp; g += 1024) {
            const int j = g * 16 + rr;           // compacted row
            const float4* src = (j < cnt)
                ? reinterpret_cast<const float4*>(x + (size_t)idx[j] * K_DIM) : nullptr;
#pragma unroll
            for (int it = 0; it < 8; ++it) {
                const int oct = op + 16 * it;    // 0..127
                float4 a, b;
                if (src) { a = src[oct * 2]; b = src[oct * 2 + 1]; }
                else { a = make_float4(0.f,0.f,0.f,0.f); b = a; }
                cvt8_store(a, b, (__bf16*)((char*)xb + frag_off(j >> 8, oct, j & 255)));
            }
        }
    } else {
        const int nz = N_ROWS - cnt;
        const int zb = blockIdx.x - 1024;        // 0..1023
        const float4 zf = make_float4(0.f, 0.f, 0.f, 0.f);
        for (int i = zb; i < nz; i += 1024) {
            const int row = zidx[i];
            float4* p = reinterpret_cast<float4*>(out + (size_t)row * N_OUT);
#pragma unroll
            for (int u = 0; u < 4; ++u)          // 256 thr x 4 float4 = 16 KB row
                p[u * 256 + t] = zf;
        }
    }
}

// ---------------- 8-phase 256x256 bf16 MFMA GEMM (R6 schedule, new sources) ---
// Schedule/ledger byte-identical to R6 (HW-correctness-verified). Only change:
// staging sources are CONTIGUOUS 8KB runs of the pre-arranged layout.
// LDS: 2 bufs x 64KB; per buf: A-kh0 @0, A-kh1 @16K, B-kh0 @32K, B-kh1 @48K.

#define GLL(SRC, DSTOFF)                                                       \
    __builtin_amdgcn_global_load_lds(                                          \
        (const __attribute__((address_space(1))) void*)(SRC),                  \
        (__attribute__((address_space(3))) void*)(ldsc + (DSTOFF)), 16, 0, 0)

#define STG_A(b, kh, kt) do {                                                  \
    GLL(pA0 + (size_t)(kt)*32768 + (kh)*16384,                                 \
        (b)*65536 + (kh)*16384 + t*16);                                        \
    GLL(pA0 + (size_t)(kt)*32768 + (kh)*16384 + 8192,                          \
        (b)*65536 + (kh)*16384 + 8192 + t*16); } while (0)
#define STG_B(b, kh, kt) do {                                                  \
    GLL(pB0 + (size_t)(kt)*32768 + (kh)*16384,                                 \
        (b)*65536 + 32768 + (kh)*16384 + t*16);                                \
    GLL(pB0 + (size_t)(kt)*32768 + (kh)*16384 + 8192,                          \
        (b)*65536 + 32768 + (kh)*16384 + 8192 + t*16); } while (0)

#define GATE6 asm volatile("s_waitcnt vmcnt(6)" ::: "memory")
#define GATE0 asm volatile("s_waitcnt vmcnt(0)" ::: "memory")
#define NOSTG ((void)0)

#define PHASE(BUFC, KS, MH, LDB, STG, GATE)                                    \
  {                                                                            \
    _Pragma("unroll") for (int m = 0; m < 4; ++m)                              \
      aR[MH][m] = *(const short8*)(lds_all + (BUFC)*32768 + (KS)*8192 +        \
                                   (wm*8 + (MH)*4 + m)*512 + l*8);             \
    if (LDB) {                                                                 \
      _Pragma("unroll") for (int n = 0; n < 4; ++n)                            \
        bR[KS][n] = *(const short8*)(lds_all + (BUFC)*32768 + 16384 +          \
                                     (KS)*8192 + (wn*4 + n)*512 + l*8);        \
    }                                                                          \
    STG;                                                                       \
    __builtin_amdgcn_s_barrier();                                              \
    __builtin_amdgcn_s_setprio(1);                                             \
    _Pragma("unroll") for (int m = 0; m < 4; ++m)                              \
      _Pragma("unroll") for (int n = 0; n < 4; ++n)                            \
        acc[(MH)*4 + m][n] = __builtin_amdgcn_mfma_f32_16x16x32_bf16(          \
            aR[MH][m], bR[KS][n], acc[(MH)*4 + m][n], 0, 0, 0);                \
    __builtin_amdgcn_s_setprio(0);                                             \
    GATE;                                                                      \
    __builtin_amdgcn_s_barrier();                                              \
  }

#define WINDOW_FULL(BC, KT)                                                    \
  PHASE(BC, 0, 0, 1, STG_A((BC)^1, 1, (KT)+1), NOSTG)                          \
  PHASE(BC, 0, 1, 0, STG_B((BC),   0, (KT)+2), NOSTG)                          \
  PHASE(BC, 1, 0, 1, STG_A((BC),   0, (KT)+2), NOSTG)                          \
  PHASE(BC, 1, 1, 0, STG_B((BC),   1, (KT)+2), GATE6)

__global__ __launch_bounds__(512, 2) void gemm_kernel(
    const __bf16* __restrict__ A,      // frag-layout compacted active rows
    const __bf16* __restrict__ B,      // frag-layout W
    const float*  __restrict__ bias,
    const int*    __restrict__ idx,
    const int*    __restrict__ count,
    float*        __restrict__ out)
{
    __shared__ short lds_all[65536];   // 128 KB: 2 bufs x 64 KB

    const int cnt = count[0];
    const int aT  = (cnt + 255) >> 8;  // active 256-row tiles
    const int tn  = blockIdx.x & 15;
    const int tm  = blockIdx.x >> 4;   // 0..63
    if (tm >= aT) return;

    const int t  = threadIdx.x;
    const int l  = t & 63;
    const int w  = t >> 6;
    const int wm = w >> 2;             // 0..1 (row half)
    const int wn = w & 3;              // 0..3 (col quarter)

    const int m0 = tm * 256;           // base in COMPACTED row space
    const int n0 = tn * 256;

    const char* pA0 = (const char*)A + (size_t)tm * 524288 + t * 16;
    const char* pB0 = (const char*)B + (size_t)tn * 524288 + t * 16;
    char* ldsc = (char*)lds_all;

    f32x4 acc[8][4] = {};
    short8 aR[2][4], bR[2][4];

    // Prologue (R6-verified): kt0 all 4 units, vmcnt(4) -> B0h0+A0h0 landed;
    // kt1 3 units, vmcnt(6) -> all of kt0 landed; barrier.
    STG_B(0, 0, 0); STG_A(0, 0, 0); STG_B(0, 1, 0); STG_A(0, 1, 0);
    asm volatile("s_waitcnt vmcnt(4)" ::: "memory");
    STG_B(1, 0, 1); STG_A(1, 0, 1); STG_B(1, 1, 1);
    asm volatile("s_waitcnt vmcnt(6)" ::: "memory");
    __builtin_amdgcn_s_barrier();

#pragma unroll 1
    for (int j = 0; j < 7; ++j) {          // windows kt = 0..13
        const int KT2 = 2 * j;
        WINDOW_FULL(0, KT2)
        WINDOW_FULL(1, KT2 + 1)
    }
    // Tail: window 14 (buf0) stages only A-kh1(15); drain gate vmcnt(0).
    PHASE(0, 0, 0, 1, STG_A(1, 1, 15), NOSTG)
    PHASE(0, 0, 1, 0, NOSTG, NOSTG)
    PHASE(0, 1, 0, 1, NOSTG, NOSTG)
    PHASE(0, 1, 1, 0, NOSTG, GATE0)
    // Window 15 (buf1): no stages, no gate.
    PHASE(1, 0, 0, 1, NOSTG, NOSTG)
    PHASE(1, 0, 1, 0, NOSTG, NOSTG)
    PHASE(1, 1, 0, 1, NOSTG, NOSTG)
    PHASE(1, 1, 1, 0, NOSTG, NOSTG)

    // Epilogue: bias add, scatter to original rows, guard padded slots.
    const int lr = l & 15;
    const int lq = l >> 4;
    float bv[4];
#pragma unroll
    for (int n = 0; n < 4; ++n) bv[n] = bias[n0 + wn*64 + n*16 + lr];

#pragma unroll
    for (int m = 0; m < 8; ++m) {
        const int slot0 = m0 + wm*128 + m*16 + lq*4;
        int rowid[4]; bool val[4];
#pragma unroll
        for (int r = 0; r < 4; ++r) {
            const int s = slot0 + r;
            val[r] = (s < cnt);
            rowid[r] = val[r] ? idx[s] : 0;
        }
#pragma unroll
        for (int n = 0; n < 4; ++n) {
            const int cc = n0 + wn*64 + n*16 + lr;
#pragma unroll
            for (int r = 0; r < 4; ++r)
                if (val[r]) out[(size_t)rowid[r] * N_OUT + cc] = acc[m][n][r] + bv[n];
        }
    }
}

// ---------------- naive fp32 fallback (only if ws too small) ------------------
__global__ void naive_kernel(const float* __restrict__ x, const float* __restrict__ W,
                             const float* __restrict__ bias, const int* __restrict__ amask,
                             float* __restrict__ out) {
    int c = blockIdx.x * blockDim.x + threadIdx.x;
    int r = blockIdx.y;
    if (c >= N_OUT) return;
    if (amask[r] == 0) { out[(size_t)r * N_OUT + c] = 0.0f; return; }
    const float* xr = x + (size_t)r * K_DIM;
    const float* wr = W + (size_t)c * K_DIM;
    float s = 0.0f;
    for (int k = 0; k < K_DIM; ++k) s += xr[k] * wr[k];
    out[(size_t)r * N_OUT + c] = s + bias[c];
}

extern "C" void kernel_launch(void* const* d_in, const int* in_sizes, int n_in,
                              void* d_out, int out_size, void* d_ws, size_t ws_size,
                              hipStream_t stream) {
    const float* x     = (const float*)d_in[0];
    const int*   amask = (const int*)d_in[1];
    const float* W     = (const float*)d_in[2];
    const float* bias  = (const float*)d_in[3];
    float*       out   = (float*)d_out;

    const size_t xb_bytes = (size_t)N_ROWS * K_DIM * 2;   // 32 MB
    const size_t wb_bytes = (size_t)N_OUT  * K_DIM * 2;   //  8 MB
    const size_t idx_bytes = (size_t)N_ROWS * 4;          // 64 KB
    const size_t need = xb_bytes + wb_bytes + 2 * idx_bytes + 256;

    if (ws_size < need) {
        dim3 g((N_OUT + 255) / 256, N_ROWS);
        naive_kernel<<<g, 256, 0, stream>>>(x, W, bias, amask, out);
        return;
    }

    __bf16* xb   = (__bf16*)d_ws;
    __bf16* wb   = (__bf16*)((char*)d_ws + xb_bytes);
    int*    idx  = (int*)((char*)d_ws + xb_bytes + wb_bytes);
    int*    zidx = idx + N_ROWS;
    int*    cnt  = zidx + N_ROWS;

    prep_kernel<<<257, 1024, 0, stream>>>(amask, W, idx, zidx, cnt, wb);
    gather_zfill_kernel<<<2048, 256, 0, stream>>>(x, idx, zidx, cnt, xb, out);
    gemm_kernel<<<1024, 512, 0, stream>>>(xb, wb, bias, idx, cnt, out);
}